// Round 1
// baseline (4062.791 us; speedup 1.0000x reference)
//
#include <hip/hip_runtime.h>
#include <math.h>

#define L_SEQ 2048
#define NB 4
#define DMODEL 256
#define NH 8
#define DHEAD 32
#define NROW (NB*L_SEQ)

// ---------------- sinusoidal positional encoding ----------------
__global__ void pe_kernel(float* __restrict__ pe) {
    int idx = blockIdx.x*256 + threadIdx.x;      // 2048*128 total
    int l = idx >> 7, m = idx & 127;
    double ang = (double)l * exp((double)m * (-9.210340371976184/128.0)); // l / 10000^(2m/256)
    pe[l*DMODEL + 2*m]   = (float)sin(ang);
    pe[l*DMODEL + 2*m+1] = (float)cos(ang);
}

// ---------------- layernorm (one wave per row) ----------------
__global__ void ln_kernel(const float* __restrict__ x, const float* __restrict__ gamma,
                          const float* __restrict__ beta, float* __restrict__ xn) {
    int lane = threadIdx.x & 63;
    int row  = blockIdx.x*4 + (threadIdx.x >> 6);
    const float4 a = *(const float4*)(x + (size_t)row*DMODEL + lane*4);
    float s  = a.x+a.y+a.z+a.w;
    float s2 = a.x*a.x+a.y*a.y+a.z*a.z+a.w*a.w;
    #pragma unroll
    for (int o = 32; o; o >>= 1) { s += __shfl_xor(s,o); s2 += __shfl_xor(s2,o); }
    float mu  = s * (1.f/DMODEL);
    float var = s2 * (1.f/DMODEL) - mu*mu;
    float rst = rsqrtf(var + 1e-3f);
    const float4 g  = *(const float4*)(gamma + lane*4);
    const float4 bt = *(const float4*)(beta  + lane*4);
    float4 o;
    o.x = (a.x-mu)*rst*g.x + bt.x;
    o.y = (a.y-mu)*rst*g.y + bt.y;
    o.z = (a.z-mu)*rst*g.z + bt.z;
    o.w = (a.w-mu)*rst*g.w + bt.w;
    *(float4*)(xn + (size_t)row*DMODEL + lane*4) = o;
}

// ---------------- fp32 GEMM body: C[M,256] = A[M,256]@W[256,256] (+bias) ----------------
// 128x128 tile, 8x8 micro-tile, K-step 8.
__device__ __forceinline__ void gemm_body(const float* __restrict__ A,
                                          const float* __restrict__ W,
                                          const float* __restrict__ bias,
                                          float* __restrict__ C, int M) {
    __shared__ float As[8][136];
    __shared__ float Ws[8][136];
    const int row0 = blockIdx.x * 128;
    if (row0 >= M) return;
    const int col0 = blockIdx.y * 128;
    const int t  = threadIdx.x;
    const int tx = t & 15, ty = t >> 4;
    float acc[8][8];
    #pragma unroll
    for (int i = 0; i < 8; ++i)
        #pragma unroll
        for (int j = 0; j < 8; ++j) acc[i][j] = 0.f;

    const int ar = t >> 1, ac4 = t & 1;
    const int wr = t >> 5, wc4 = t & 31;

    for (int k0 = 0; k0 < 256; k0 += 8) {
        float4 av = *(const float4*)(A + (size_t)(row0+ar)*256 + k0 + ac4*4);
        As[ac4*4+0][ar] = av.x;
        As[ac4*4+1][ar] = av.y;
        As[ac4*4+2][ar] = av.z;
        As[ac4*4+3][ar] = av.w;
        *(float4*)&Ws[wr][wc4*4] = *(const float4*)(W + (size_t)(k0+wr)*256 + col0 + wc4*4);
        __syncthreads();
        #pragma unroll
        for (int kk = 0; kk < 8; ++kk) {
            float a8[8], b8[8];
            *(float4*)&a8[0] = *(const float4*)&As[kk][ty*8];
            *(float4*)&a8[4] = *(const float4*)&As[kk][ty*8+4];
            *(float4*)&b8[0] = *(const float4*)&Ws[kk][tx*8];
            *(float4*)&b8[4] = *(const float4*)&Ws[kk][tx*8+4];
            #pragma unroll
            for (int i = 0; i < 8; ++i)
                #pragma unroll
                for (int j = 0; j < 8; ++j)
                    acc[i][j] += a8[i]*b8[j];
        }
        __syncthreads();
    }
    #pragma unroll
    for (int i = 0; i < 8; ++i) {
        const int rr = row0 + ty*8 + i;
        #pragma unroll
        for (int j4 = 0; j4 < 2; ++j4) {
            const int cc = col0 + tx*8 + j4*4;
            float4 o;
            o.x = acc[i][j4*4+0] + (bias ? bias[cc+0] : 0.f);
            o.y = acc[i][j4*4+1] + (bias ? bias[cc+1] : 0.f);
            o.z = acc[i][j4*4+2] + (bias ? bias[cc+2] : 0.f);
            o.w = acc[i][j4*4+3] + (bias ? bias[cc+3] : 0.f);
            *(float4*)(C + (size_t)rr*256 + cc) = o;
        }
    }
}

__global__ __launch_bounds__(256)
void proj_kernel(const float* __restrict__ xn, const float* __restrict__ pe,
                 const float* __restrict__ Wq, const float* __restrict__ bq,
                 const float* __restrict__ Wk, const float* __restrict__ bk,
                 const float* __restrict__ Wv, const float* __restrict__ bv,
                 const float* __restrict__ Wp,
                 float* __restrict__ q, float* __restrict__ k,
                 float* __restrict__ v, float* __restrict__ p) {
    const float* A; const float* W; const float* bias; float* C; int M;
    switch (blockIdx.z) {
        case 0:  A = xn; W = Wq; bias = bq;      C = q; M = NROW;  break;
        case 1:  A = xn; W = Wk; bias = bk;      C = k; M = NROW;  break;
        case 2:  A = xn; W = Wv; bias = bv;      C = v; M = NROW;  break;
        default: A = pe; W = Wp; bias = nullptr; C = p; M = L_SEQ; break;
    }
    gemm_body(A, W, bias, C, M);
}

__global__ __launch_bounds__(256)
void gemm_kernel(const float* __restrict__ A, const float* __restrict__ W,
                 const float* __restrict__ bias, float* __restrict__ C, int M) {
    gemm_body(A, W, bias, C, M);
}

// ---------------- fused flash-style attention with Transformer-XL rel-shift ----------------
// Block = 256 threads, one (batch, head, 64-row q-tile). Iterates 64-key tiles.
// rel_shift: shifted[q,k] = X[q, L-1-q+k] (k<=q), 0 (k==q+1), X[q+1, k-q-2] (k>q+1),
// with X[r,m] = (q_r + v_bias) . p_m.  Using rho = k-q-2: ptilde[rho] = (rho==-1 ? 0 :
// rho>=0 ? p[rho] : p[rho+L+1]), q-row = q + (rho>=0).  Window index jj = ki-qi+63 in [0,126].
__global__ __launch_bounds__(256)
void attn_kernel(const float* __restrict__ qg, const float* __restrict__ kg,
                 const float* __restrict__ vg, const float* __restrict__ pg,
                 const float* __restrict__ ub, const float* __restrict__ vb,
                 float* __restrict__ ctx) {
    const int q0 = blockIdx.x * 64;
    const int h  = blockIdx.y;
    const int b  = blockIdx.z;
    const int t  = threadIdx.x;

    __shared__ float sQ[65][36];     // q rows q0..q0+64 (row 64 zero-padded at last tile)
    __shared__ float sK[64][36];
    __shared__ float sV[64][36];
    __shared__ float sPB[128*36];    // ptilde window (stride 36); reused as P tile (stride 72)
    __shared__ float sUB[32], sVBs[32];
    __shared__ float sUK[64], sVP[128];
    __shared__ float sM[64], sL[64], sAl[64];

    if (t < 32) sUB[t] = ub[h*DHEAD + t];
    else if (t < 64) sVBs[t-32] = vb[h*DHEAD + (t-32)];
    if (t < 64) { sM[t] = -3.0e38f; sL[t] = 0.f; }

    for (int sI = t; sI < 65*8; sI += 256) {
        int r = sI >> 3, c4 = sI & 7;
        float4 val = make_float4(0.f,0.f,0.f,0.f);
        if (q0 + r < L_SEQ)
            val = *(const float4*)(qg + (size_t)(b*L_SEQ + q0 + r)*DMODEL + h*DHEAD + c4*4);
        *(float4*)&sQ[r][c4*4] = val;
    }

    float acc[8];
    #pragma unroll
    for (int i = 0; i < 8; ++i) acc[i] = 0.f;

    const int tx = t & 15, ty = t >> 4;    // score pass: qi = 4*ty+i, ki = tx+16*j
    const int dcol = t & 31, g8 = t >> 5;  // ctx pass: d = dcol, qi = 8*g8+jr

    for (int k0 = 0; k0 < L_SEQ; k0 += 64) {
        const int jbase = k0 - q0 - 65;    // rho = jbase + jj
        // ---- stage K, V tiles ----
        for (int sI = t; sI < 512; sI += 256) {
            int r = sI >> 3, c4 = sI & 7;
            size_t go = (size_t)(b*L_SEQ + k0 + r)*DMODEL + h*DHEAD + c4*4;
            *(float4*)&sK[r][c4*4] = *(const float4*)(kg + go);
            *(float4*)&sV[r][c4*4] = *(const float4*)(vg + go);
        }
        // ---- stage ptilde window (127 rows + zero pad row) ----
        for (int sI = t; sI < 1024; sI += 256) {
            int j = sI >> 3, c4 = sI & 7;
            int rho = jbase + j;
            float4 val = make_float4(0.f,0.f,0.f,0.f);
            if (j < 127 && rho != -1) {
                int pr = (rho >= 0) ? rho : rho + (L_SEQ+1);
                val = *(const float4*)(pg + (size_t)pr*DMODEL + h*DHEAD + c4*4);
            }
            *(float4*)&sPB[j*36 + c4*4] = val;
        }
        __syncthreads();
        // ---- bias dot vectors: u.k per ki, v_bias.ptilde per jj ----
        if (t < 64) {
            float sum = 0.f;
            #pragma unroll
            for (int d = 0; d < 32; ++d) sum += sUB[d]*sK[t][d];
            sUK[t] = sum;
        } else if (t < 192) {
            int j = t - 64;
            float sum = 0.f;
            #pragma unroll
            for (int d = 0; d < 32; ++d) sum += sVBs[d]*sPB[j*36 + d];
            sVP[j] = sum;
        }
        __syncthreads();
        // ---- scores: content (q.k) + pos (q_sel . ptilde), 4x4 per thread ----
        float sc[4][4];
        #pragma unroll
        for (int i = 0; i < 4; ++i)
            #pragma unroll
            for (int j = 0; j < 4; ++j) sc[i][j] = 0.f;
        #pragma unroll
        for (int d4 = 0; d4 < 8; ++d4) {
            float4 qreg[5], kreg[4];
            #pragma unroll
            for (int i = 0; i < 5; ++i) qreg[i] = *(const float4*)&sQ[ty*4+i][d4*4];
            #pragma unroll
            for (int j = 0; j < 4; ++j) kreg[j] = *(const float4*)&sK[tx+16*j][d4*4];
            #pragma unroll
            for (int i = 0; i < 4; ++i) {
                #pragma unroll
                for (int j = 0; j < 4; ++j) {
                    int jj = (tx+16*j) - (ty*4+i) + 63;
                    float4 pbv = *(const float4*)&sPB[jj*36 + d4*4];
                    bool up = (jbase + jj) >= 0;
                    float qpx = up ? qreg[i+1].x : qreg[i].x;
                    float qpy = up ? qreg[i+1].y : qreg[i].y;
                    float qpz = up ? qreg[i+1].z : qreg[i].z;
                    float qpw = up ? qreg[i+1].w : qreg[i].w;
                    sc[i][j] += qreg[i].x*kreg[j].x + qreg[i].y*kreg[j].y
                              + qreg[i].z*kreg[j].z + qreg[i].w*kreg[j].w
                              + qpx*pbv.x + qpy*pbv.y + qpz*pbv.z + qpw*pbv.w;
                }
            }
        }
        // ---- finalize scores + online softmax (16-lane row groups) ----
        #pragma unroll
        for (int i = 0; i < 4; ++i) {
            int qi = ty*4 + i;
            #pragma unroll
            for (int j = 0; j < 4; ++j) {
                int ki = tx + 16*j;
                int jj = ki - qi + 63;
                sc[i][j] = (sc[i][j] + sUK[ki] + sVP[jj]) * 0.0625f;
            }
            float m4 = fmaxf(fmaxf(sc[i][0],sc[i][1]), fmaxf(sc[i][2],sc[i][3]));
            #pragma unroll
            for (int o = 8; o; o >>= 1) m4 = fmaxf(m4, __shfl_xor(m4, o));
            float oldm = sM[qi];
            float newm = fmaxf(oldm, m4);
            float ts = 0.f;
            #pragma unroll
            for (int j = 0; j < 4; ++j) { sc[i][j] = __expf(sc[i][j] - newm); ts += sc[i][j]; }
            #pragma unroll
            for (int o = 8; o; o >>= 1) ts += __shfl_xor(ts, o);
            if (tx == 0) {
                float al = __expf(oldm - newm);
                sAl[qi] = al;
                sM[qi]  = newm;
                sL[qi]  = sL[qi]*al + ts;
            }
        }
        __syncthreads();                       // all sPB window reads done
        // ---- store P tile into sPB space (stride 72) ----
        #pragma unroll
        for (int i = 0; i < 4; ++i)
            #pragma unroll
            for (int j = 0; j < 4; ++j)
                sPB[(ty*4+i)*72 + (tx+16*j)] = sc[i][j];
        __syncthreads();
        // ---- ctx accumulate: acc[qi][d] = acc*alpha + P.V ----
        {
            float vcol[64];
            #pragma unroll
            for (int ki = 0; ki < 64; ++ki) vcol[ki] = sV[ki][dcol];
            #pragma unroll
            for (int jr = 0; jr < 8; ++jr) {
                int qi = g8*8 + jr;
                float sum = 0.f;
                #pragma unroll
                for (int k4 = 0; k4 < 16; ++k4) {
                    float4 pv = *(const float4*)&sPB[qi*72 + k4*4];
                    sum += pv.x*vcol[k4*4] + pv.y*vcol[k4*4+1]
                         + pv.z*vcol[k4*4+2] + pv.w*vcol[k4*4+3];
                }
                acc[jr] = acc[jr]*sAl[qi] + sum;
            }
        }
        __syncthreads();                       // before next tile overwrites LDS
    }
    #pragma unroll
    for (int jr = 0; jr < 8; ++jr) {
        int qi = g8*8 + jr;
        ctx[(size_t)(b*L_SEQ + q0 + qi)*DMODEL + h*DHEAD + dcol] = acc[jr] / sL[qi];
    }
}

extern "C" void kernel_launch(void* const* d_in, const int* in_sizes, int n_in,
                              void* d_out, int out_size, void* d_ws, size_t ws_size,
                              hipStream_t stream) {
    (void)in_sizes; (void)n_in; (void)out_size; (void)ws_size;
    const float* x     = (const float*)d_in[0];
    const float* gamma = (const float*)d_in[1];
    const float* beta  = (const float*)d_in[2];
    const float* Wq    = (const float*)d_in[3];
    const float* bq    = (const float*)d_in[4];
    const float* Wk    = (const float*)d_in[5];
    const float* bk    = (const float*)d_in[6];
    const float* Wv    = (const float*)d_in[7];
    const float* bv    = (const float*)d_in[8];
    const float* Wp    = (const float*)d_in[9];
    const float* ub    = (const float*)d_in[10];
    const float* vb    = (const float*)d_in[11];
    const float* Wo    = (const float*)d_in[12];
    const float* bo    = (const float*)d_in[13];
    float* out = (float*)d_out;

    float* ws  = (float*)d_ws;
    float* xn  = ws;                               // [8192,256]; reused as ctx afterwards
    float* ctx = ws;
    float* pe  = ws + (size_t)NROW*DMODEL;         // [2048,256]
    float* q   = pe + (size_t)L_SEQ*DMODEL;        // [8192,256]
    float* k   = q  + (size_t)NROW*DMODEL;
    float* v   = k  + (size_t)NROW*DMODEL;
    float* p   = v  + (size_t)NROW*DMODEL;         // [2048,256]

    pe_kernel<<<1024, 256, 0, stream>>>(pe);
    ln_kernel<<<2048, 256, 0, stream>>>(x, gamma, beta, xn);
    proj_kernel<<<dim3(64,2,4), 256, 0, stream>>>(xn, pe, Wq, bq, Wk, bk, Wv, bv, Wp, q, k, v, p);
    attn_kernel<<<dim3(32,8,4), 256, 0, stream>>>(q, k, v, p, ub, vb, ctx);
    gemm_kernel<<<dim3(64,2,1), 256, 0, stream>>>(ctx, Wo, bo, out, NROW);
}

// Round 2
// 565.043 us; speedup vs baseline: 7.1902x; 7.1902x over previous
//
#include <hip/hip_runtime.h>
#include <hip/hip_bf16.h>
#include <math.h>

#define L_SEQ 2048
#define NB 4
#define DMODEL 256
#define NH 8
#define DHEAD 32
#define NROW (NB*L_SEQ)

typedef __attribute__((ext_vector_type(8))) short short8;
typedef __attribute__((ext_vector_type(4))) float f32x4;

__device__ __forceinline__ float bf2f(short v) {
    union { unsigned u; float f; } x; x.u = ((unsigned)(unsigned short)v) << 16; return x.f;
}
__device__ __forceinline__ short f2bf(float f) {
    union { float f; unsigned u; } x; x.f = f;
    unsigned r = x.u + 0x7fff + ((x.u >> 16) & 1);
    return (short)(r >> 16);
}
__device__ __forceinline__ short8 zero8() {
    short8 z;
    #pragma unroll
    for (int i = 0; i < 8; ++i) z[i] = 0;
    return z;
}

// ---------------- sinusoidal positional encoding ----------------
__global__ void pe_kernel(float* __restrict__ pe) {
    int idx = blockIdx.x*256 + threadIdx.x;      // 2048*128 total
    int l = idx >> 7, m = idx & 127;
    double ang = (double)l * exp((double)m * (-9.210340371976184/128.0));
    pe[l*DMODEL + 2*m]   = (float)sin(ang);
    pe[l*DMODEL + 2*m+1] = (float)cos(ang);
}

// ---------------- layernorm (one wave per row) ----------------
__global__ void ln_kernel(const float* __restrict__ x, const float* __restrict__ gamma,
                          const float* __restrict__ beta, float* __restrict__ xn) {
    int lane = threadIdx.x & 63;
    int row  = blockIdx.x*4 + (threadIdx.x >> 6);
    const float4 a = *(const float4*)(x + (size_t)row*DMODEL + lane*4);
    float s  = a.x+a.y+a.z+a.w;
    float s2 = a.x*a.x+a.y*a.y+a.z*a.z+a.w*a.w;
    #pragma unroll
    for (int o = 32; o; o >>= 1) { s += __shfl_xor(s,o); s2 += __shfl_xor(s2,o); }
    float mu  = s * (1.f/DMODEL);
    float var = s2 * (1.f/DMODEL) - mu*mu;
    float rst = rsqrtf(var + 1e-3f);
    const float4 g  = *(const float4*)(gamma + lane*4);
    const float4 bt = *(const float4*)(beta  + lane*4);
    float4 o;
    o.x = (a.x-mu)*rst*g.x + bt.x;
    o.y = (a.y-mu)*rst*g.y + bt.y;
    o.z = (a.z-mu)*rst*g.z + bt.z;
    o.w = (a.w-mu)*rst*g.w + bt.w;
    *(float4*)(xn + (size_t)row*DMODEL + lane*4) = o;
}

// ---------------- fp32 GEMM core (128x128 tile, 8x8 micro) ----------------
__device__ __forceinline__ void gemm_core(const float* __restrict__ A,
                                          const float* __restrict__ W,
                                          int row0, int col0, float acc[8][8]) {
    __shared__ float As[8][136];
    __shared__ float Ws[8][136];
    const int t  = threadIdx.x;
    const int tx = t & 15, ty = t >> 4;
    #pragma unroll
    for (int i = 0; i < 8; ++i)
        #pragma unroll
        for (int j = 0; j < 8; ++j) acc[i][j] = 0.f;

    const int ar = t >> 1, ac4 = t & 1;
    const int wr = t >> 5, wc4 = t & 31;

    for (int k0 = 0; k0 < 256; k0 += 8) {
        float4 av = *(const float4*)(A + (size_t)(row0+ar)*256 + k0 + ac4*4);
        As[ac4*4+0][ar] = av.x;
        As[ac4*4+1][ar] = av.y;
        As[ac4*4+2][ar] = av.z;
        As[ac4*4+3][ar] = av.w;
        *(float4*)&Ws[wr][wc4*4] = *(const float4*)(W + (size_t)(k0+wr)*256 + col0 + wc4*4);
        __syncthreads();
        #pragma unroll
        for (int kk = 0; kk < 8; ++kk) {
            float a8[8], b8[8];
            *(float4*)&a8[0] = *(const float4*)&As[kk][ty*8];
            *(float4*)&a8[4] = *(const float4*)&As[kk][ty*8+4];
            *(float4*)&b8[0] = *(const float4*)&Ws[kk][tx*8];
            *(float4*)&b8[4] = *(const float4*)&Ws[kk][tx*8+4];
            #pragma unroll
            for (int i = 0; i < 8; ++i)
                #pragma unroll
                for (int j = 0; j < 8; ++j)
                    acc[i][j] += a8[i]*b8[j];
        }
        __syncthreads();
    }
}

// ---------------- projections -> bf16 (qu = q+u, qv = q+v_bias, k, v, p) ----------------
__global__ __launch_bounds__(256)
void proj_kernel(const float* __restrict__ xn, const float* __restrict__ pe,
                 const float* __restrict__ Wq, const float* __restrict__ bq,
                 const float* __restrict__ Wk, const float* __restrict__ bk,
                 const float* __restrict__ Wv, const float* __restrict__ bv,
                 const float* __restrict__ Wp,
                 const float* __restrict__ ub, const float* __restrict__ vb,
                 short* __restrict__ qu, short* __restrict__ qv,
                 short* __restrict__ kb, short* __restrict__ vbuf,
                 short* __restrict__ pbuf) {
    const int z = blockIdx.z;
    const float* A; const float* W; int M;
    switch (z) {
        case 0:  A = xn; W = Wq; M = NROW;  break;
        case 1:  A = xn; W = Wk; M = NROW;  break;
        case 2:  A = xn; W = Wv; M = NROW;  break;
        default: A = pe; W = Wp; M = L_SEQ; break;
    }
    const int row0 = blockIdx.x * 128;
    if (row0 >= M) return;
    const int col0 = blockIdx.y * 128;
    float acc[8][8];
    gemm_core(A, W, row0, col0, acc);

    const int t = threadIdx.x;
    const int tx = t & 15, ty = t >> 4;
    #pragma unroll
    for (int i = 0; i < 8; ++i) {
        const int rr = row0 + ty*8 + i;
        #pragma unroll
        for (int j = 0; j < 8; ++j) {
            const int cc = col0 + tx*8 + j;
            const float a = acc[i][j];
            const size_t idx = (size_t)rr*DMODEL + cc;
            if (z == 0) {
                const float base = a + bq[cc];
                qu[idx] = f2bf(base + ub[cc]);
                qv[idx] = f2bf(base + vb[cc]);
            } else if (z == 1) {
                kb[idx] = f2bf(a + bk[cc]);
            } else if (z == 2) {
                vbuf[idx] = f2bf(a + bv[cc]);
            } else {
                pbuf[idx] = f2bf(a);
            }
        }
    }
}

// ---------------- final out GEMM (fp32) ----------------
__global__ __launch_bounds__(256)
void gemm_kernel(const float* __restrict__ A, const float* __restrict__ W,
                 const float* __restrict__ bias, float* __restrict__ C, int M) {
    const int row0 = blockIdx.x * 128;
    if (row0 >= M) return;
    const int col0 = blockIdx.y * 128;
    float acc[8][8];
    gemm_core(A, W, row0, col0, acc);
    const int t = threadIdx.x;
    const int tx = t & 15, ty = t >> 4;
    #pragma unroll
    for (int i = 0; i < 8; ++i) {
        const int rr = row0 + ty*8 + i;
        #pragma unroll
        for (int j4 = 0; j4 < 2; ++j4) {
            const int cc = col0 + tx*8 + j4*4;
            float4 o;
            o.x = acc[i][j4*4+0] + bias[cc+0];
            o.y = acc[i][j4*4+1] + bias[cc+1];
            o.z = acc[i][j4*4+2] + bias[cc+2];
            o.w = acc[i][j4*4+3] + bias[cc+3];
            *(float4*)(C + (size_t)rr*256 + cc) = o;
        }
    }
}

// ---------------- V transpose: v[b,l,h,d] -> vT[b,h,d,l] ----------------
__global__ __launch_bounds__(256)
void vtrans_kernel(const short* __restrict__ v, short* __restrict__ vT) {
    const int l0 = blockIdx.x * 64;
    const int h  = blockIdx.y;
    const int b  = blockIdx.z;
    const int t  = threadIdx.x;
    __shared__ short s[32][72];
    const int r = t & 63, c8 = (t >> 6) * 8;
    short8 val = *(const short8*)(v + ((size_t)(b*L_SEQ + l0 + r))*DMODEL + h*DHEAD + c8);
    #pragma unroll
    for (int j = 0; j < 8; ++j) s[c8+j][r] = val[j];
    __syncthreads();
    const int d = t >> 3, l8 = (t & 7) * 8;
    *(short8*)(vT + (((size_t)((b*NH + h)*DHEAD + d))*L_SEQ) + l0 + l8) = *(const short8*)&s[d][l8];
}

// ---------------- fused MFMA attention with Transformer-XL rel-shift ----------------
// Block = 256 threads (4 waves), one (b, h, 64-row q-tile).
// Per 64-key tile: 4 content MFMA (qu.k), 8 pos-band MFMA T[qi,jj]=qv.ptilde[jj] -> LDS
// transposed, VALU row T[64], gather S = (C + T[qi+up][ki-qi+63])/16, online softmax in
// registers, P->LDS bf16, 4 PV MFMA (B from global vT).
__global__ __launch_bounds__(256, 3)
void attn_mfma_kernel(const short* __restrict__ qu, const short* __restrict__ qv,
                      const short* __restrict__ kb, const short* __restrict__ pb,
                      const short* __restrict__ vT, float* __restrict__ ctx) {
    const int q0 = blockIdx.x * 64;
    const int h  = blockIdx.y;
    const int b  = blockIdx.z;
    const int t  = threadIdx.x;
    const int w  = t >> 6;
    const int l  = t & 63;
    const int lc = l & 15;
    const int lg = l >> 4;

    __shared__ float sTt[128][68];   // [jj][qi 0..64] pos scores (transposed)
    __shared__ short sP[64][72];     // softmax probs, bf16

    // A-fragments: rows q0+16w+lc, k = lg*8..+8 (held across all k-tiles)
    const size_t qrow = ((size_t)(b*L_SEQ + q0 + 16*w + lc))*DMODEL + h*DHEAD + lg*8;
    const short8 aqu = *(const short8*)(qu + qrow);
    const short8 aqv = *(const short8*)(qv + qrow);

    // qv row q0+64 for the extra T row (threads 0..127)
    short8 q64r[4];
    if (t < 128) {
        if (q0 + 64 < L_SEQ) {
            const short* p64 = qv + ((size_t)(b*L_SEQ + q0 + 64))*DMODEL + h*DHEAD;
            #pragma unroll
            for (int c = 0; c < 4; ++c) q64r[c] = *(const short8*)(p64 + c*8);
        } else {
            #pragma unroll
            for (int c = 0; c < 4; ++c) q64r[c] = zero8();
        }
    }

    float m_r[4], l_r[4], alpha[4];
    f32x4 acc0, acc1;
    #pragma unroll
    for (int r = 0; r < 4; ++r) { m_r[r] = -3.0e38f; l_r[r] = 0.f; acc0[r] = 0.f; acc1[r] = 0.f; }

    const short* kbase = kb + ((size_t)(b*L_SEQ))*DMODEL + h*DHEAD;
    const short* pbase = pb + h*DHEAD;
    const short* vbase = vT + ((size_t)((b*NH + h)*DHEAD))*L_SEQ;
    const f32x4 zf = {0.f, 0.f, 0.f, 0.f};

    for (int k0 = 0; k0 < L_SEQ; k0 += 64) {
        const int jbase = k0 - q0 - 65;   // rho = jbase + jj

        // ---- content scores: 4 col tiles ----
        f32x4 c[4];
        #pragma unroll
        for (int ct = 0; ct < 4; ++ct) {
            const short8 bk = *(const short8*)(kbase + (size_t)(k0 + ct*16 + lc)*DMODEL + lg*8);
            c[ct] = __builtin_amdgcn_mfma_f32_16x16x32_bf16(aqu, bk, zf, 0, 0, 0);
        }
        // ---- pos band: T[qi][jj] for jj in [0,128) -> sTt ----
        #pragma unroll
        for (int ct = 0; ct < 8; ++ct) {
            const int jj = ct*16 + lc;
            const int rho = jbase + jj;
            short8 bp;
            if (rho == -1) bp = zero8();
            else {
                const int pr = rho + (rho < 0 ? (L_SEQ+1) : 0);
                bp = *(const short8*)(pbase + (size_t)pr*DMODEL + lg*8);
            }
            f32x4 tt = __builtin_amdgcn_mfma_f32_16x16x32_bf16(aqv, bp, zf, 0, 0, 0);
            *(f32x4*)&sTt[jj][16*w + lg*4] = tt;
        }
        // ---- extra T row (qi = 64) via VALU ----
        if (t < 128) {
            const int jj = t;
            const int rho = jbase + jj;
            float sum = 0.f;
            if (rho != -1) {
                const int pr = rho + (rho < 0 ? (L_SEQ+1) : 0);
                const short* prow = pbase + (size_t)pr*DMODEL;
                #pragma unroll
                for (int cc4 = 0; cc4 < 4; ++cc4) {
                    short8 pv = *(const short8*)(prow + cc4*8);
                    #pragma unroll
                    for (int j = 0; j < 8; ++j) sum += bf2f(q64r[cc4][j]) * bf2f(pv[j]);
                }
            }
            sTt[jj][64] = sum;
        }
        __syncthreads();

        // ---- combine + online softmax (state in regs; row = 16w + lg*4 + r) ----
        #pragma unroll
        for (int r = 0; r < 4; ++r) {
            const int qi = 16*w + lg*4 + r;
            float sc[4];
            #pragma unroll
            for (int ct = 0; ct < 4; ++ct) {
                const int ki = ct*16 + lc;
                const int jj = ki - qi + 63;
                const int up = (jbase + jj) >= 0 ? 1 : 0;
                sc[ct] = (c[ct][r] + sTt[jj][qi + up]) * 0.0625f;
            }
            float mx = fmaxf(fmaxf(sc[0], sc[1]), fmaxf(sc[2], sc[3]));
            #pragma unroll
            for (int o = 8; o; o >>= 1) mx = fmaxf(mx, __shfl_xor(mx, o));
            const float mn = fmaxf(m_r[r], mx);
            float ts = 0.f;
            #pragma unroll
            for (int ct = 0; ct < 4; ++ct) { sc[ct] = __expf(sc[ct] - mn); ts += sc[ct]; }
            #pragma unroll
            for (int o = 8; o; o >>= 1) ts += __shfl_xor(ts, o);
            alpha[r] = __expf(m_r[r] - mn);
            m_r[r] = mn;
            l_r[r] = l_r[r]*alpha[r] + ts;
            #pragma unroll
            for (int ct = 0; ct < 4; ++ct) sP[qi][ct*16 + lc] = f2bf(sc[ct]);
        }
        #pragma unroll
        for (int r = 0; r < 4; ++r) { acc0[r] *= alpha[r]; acc1[r] *= alpha[r]; }

        // ---- PV: A = own P rows (LDS), B = vT (global) ----
        #pragma unroll
        for (int kc = 0; kc < 2; ++kc) {
            const short8 ap = *(const short8*)&sP[16*w + lc][kc*32 + lg*8];
            const short8 bv0 = *(const short8*)(vbase + (size_t)(lc)*L_SEQ + k0 + kc*32 + lg*8);
            acc0 = __builtin_amdgcn_mfma_f32_16x16x32_bf16(ap, bv0, acc0, 0, 0, 0);
            const short8 bv1 = *(const short8*)(vbase + (size_t)(16 + lc)*L_SEQ + k0 + kc*32 + lg*8);
            acc1 = __builtin_amdgcn_mfma_f32_16x16x32_bf16(ap, bv1, acc1, 0, 0, 0);
        }
        __syncthreads();   // protect sTt before next tile's writes
    }

    #pragma unroll
    for (int r = 0; r < 4; ++r) {
        const float inv = 1.f / l_r[r];
        const size_t orow = ((size_t)(b*L_SEQ + q0 + 16*w + lg*4 + r))*DMODEL + h*DHEAD;
        ctx[orow + lc]      = acc0[r] * inv;
        ctx[orow + 16 + lc] = acc1[r] * inv;
    }
}

extern "C" void kernel_launch(void* const* d_in, const int* in_sizes, int n_in,
                              void* d_out, int out_size, void* d_ws, size_t ws_size,
                              hipStream_t stream) {
    (void)in_sizes; (void)n_in; (void)out_size; (void)ws_size;
    const float* x     = (const float*)d_in[0];
    const float* gamma = (const float*)d_in[1];
    const float* beta  = (const float*)d_in[2];
    const float* Wq    = (const float*)d_in[3];
    const float* bq    = (const float*)d_in[4];
    const float* Wk    = (const float*)d_in[5];
    const float* bk    = (const float*)d_in[6];
    const float* Wv    = (const float*)d_in[7];
    const float* bv    = (const float*)d_in[8];
    const float* Wp    = (const float*)d_in[9];
    const float* ub    = (const float*)d_in[10];
    const float* vb    = (const float*)d_in[11];
    const float* Wo    = (const float*)d_in[12];
    const float* bo    = (const float*)d_in[13];
    float* out = (float*)d_out;

    char* wsb = (char*)d_ws;
    float* ctx = (float*)wsb;                                   // 8192*256 f32 (aliases xn)
    float* xn  = ctx;
    float* pe  = (float*)(wsb + (size_t)8388608);               // 2048*256 f32
    short* qu  = (short*)(wsb + (size_t)8388608 + 2097152);     // bf16 buffers
    short* qv  = qu + (size_t)NROW*DMODEL;
    short* kbf = qv + (size_t)NROW*DMODEL;
    short* vbf = kbf + (size_t)NROW*DMODEL;
    short* vT  = vbf + (size_t)NROW*DMODEL;
    short* pbf = vT  + (size_t)NROW*DMODEL;                     // 2048*256 bf16

    pe_kernel<<<1024, 256, 0, stream>>>(pe);
    ln_kernel<<<2048, 256, 0, stream>>>(x, gamma, beta, xn);
    proj_kernel<<<dim3(64,2,4), 256, 0, stream>>>(xn, pe, Wq, bq, Wk, bk, Wv, bv, Wp,
                                                  ub, vb, qu, qv, kbf, vbf, pbf);
    vtrans_kernel<<<dim3(32,8,4), 256, 0, stream>>>(vbf, vT);
    attn_mfma_kernel<<<dim3(32,8,4), 256, 0, stream>>>(qu, qv, kbf, pbf, vT, ctx);
    gemm_kernel<<<dim3(64,2,1), 256, 0, stream>>>(ctx, Wo, bo, out, NROW);
}

// Round 3
// 380.202 us; speedup vs baseline: 10.6859x; 1.4862x over previous
//
#include <hip/hip_runtime.h>
#include <hip/hip_bf16.h>
#include <math.h>

#define L_SEQ 2048
#define NB 4
#define DMODEL 256
#define NH 8
#define DHEAD 32
#define NROW (NB*L_SEQ)

typedef __attribute__((ext_vector_type(8))) short short8;
typedef __attribute__((ext_vector_type(4))) float f32x4;

__device__ __forceinline__ float bf2f(short v) {
    union { unsigned u; float f; } x; x.u = ((unsigned)(unsigned short)v) << 16; return x.f;
}
__device__ __forceinline__ short f2bf(float f) {
    union { float f; unsigned u; } x; x.f = f;
    unsigned r = x.u + 0x7fff + ((x.u >> 16) & 1);
    return (short)(r >> 16);
}
__device__ __forceinline__ short8 zero8() {
    short8 z;
    #pragma unroll
    for (int i = 0; i < 8; ++i) z[i] = 0;
    return z;
}

// ---------------- sinusoidal positional encoding ----------------
__global__ void pe_kernel(float* __restrict__ pe) {
    int idx = blockIdx.x*256 + threadIdx.x;      // 2048*128 total
    int l = idx >> 7, m = idx & 127;
    double ang = (double)l * exp((double)m * (-9.210340371976184/128.0));
    pe[l*DMODEL + 2*m]   = (float)sin(ang);
    pe[l*DMODEL + 2*m+1] = (float)cos(ang);
}

// ---------------- layernorm (one wave per row) ----------------
__global__ void ln_kernel(const float* __restrict__ x, const float* __restrict__ gamma,
                          const float* __restrict__ beta, float* __restrict__ xn) {
    int lane = threadIdx.x & 63;
    int row  = blockIdx.x*4 + (threadIdx.x >> 6);
    const float4 a = *(const float4*)(x + (size_t)row*DMODEL + lane*4);
    float s  = a.x+a.y+a.z+a.w;
    float s2 = a.x*a.x+a.y*a.y+a.z*a.z+a.w*a.w;
    #pragma unroll
    for (int o = 32; o; o >>= 1) { s += __shfl_xor(s,o); s2 += __shfl_xor(s2,o); }
    float mu  = s * (1.f/DMODEL);
    float var = s2 * (1.f/DMODEL) - mu*mu;
    float rst = rsqrtf(var + 1e-3f);
    const float4 g  = *(const float4*)(gamma + lane*4);
    const float4 bt = *(const float4*)(beta  + lane*4);
    float4 o;
    o.x = (a.x-mu)*rst*g.x + bt.x;
    o.y = (a.y-mu)*rst*g.y + bt.y;
    o.z = (a.z-mu)*rst*g.z + bt.z;
    o.w = (a.w-mu)*rst*g.w + bt.w;
    *(float4*)(xn + (size_t)row*DMODEL + lane*4) = o;
}

// ---------------- fp32 GEMM core (128x128 tile, 8x8 micro) ----------------
__device__ __forceinline__ void gemm_core(const float* __restrict__ A,
                                          const float* __restrict__ W,
                                          int row0, int col0, float acc[8][8]) {
    __shared__ float As[8][136];
    __shared__ float Ws[8][136];
    const int t  = threadIdx.x;
    const int tx = t & 15, ty = t >> 4;
    #pragma unroll
    for (int i = 0; i < 8; ++i)
        #pragma unroll
        for (int j = 0; j < 8; ++j) acc[i][j] = 0.f;

    const int ar = t >> 1, ac4 = t & 1;
    const int wr = t >> 5, wc4 = t & 31;

    for (int k0 = 0; k0 < 256; k0 += 8) {
        float4 av = *(const float4*)(A + (size_t)(row0+ar)*256 + k0 + ac4*4);
        As[ac4*4+0][ar] = av.x;
        As[ac4*4+1][ar] = av.y;
        As[ac4*4+2][ar] = av.z;
        As[ac4*4+3][ar] = av.w;
        *(float4*)&Ws[wr][wc4*4] = *(const float4*)(W + (size_t)(k0+wr)*256 + col0 + wc4*4);
        __syncthreads();
        #pragma unroll
        for (int kk = 0; kk < 8; ++kk) {
            float a8[8], b8[8];
            *(float4*)&a8[0] = *(const float4*)&As[kk][ty*8];
            *(float4*)&a8[4] = *(const float4*)&As[kk][ty*8+4];
            *(float4*)&b8[0] = *(const float4*)&Ws[kk][tx*8];
            *(float4*)&b8[4] = *(const float4*)&Ws[kk][tx*8+4];
            #pragma unroll
            for (int i = 0; i < 8; ++i)
                #pragma unroll
                for (int j = 0; j < 8; ++j)
                    acc[i][j] += a8[i]*b8[j];
        }
        __syncthreads();
    }
}

// ---------------- projections -> bf16 (qu = q+u, qv = q+v_bias, k, v, p) ----------------
__global__ __launch_bounds__(256)
void proj_kernel(const float* __restrict__ xn, const float* __restrict__ pe,
                 const float* __restrict__ Wq, const float* __restrict__ bq,
                 const float* __restrict__ Wk, const float* __restrict__ bk,
                 const float* __restrict__ Wv, const float* __restrict__ bv,
                 const float* __restrict__ Wp,
                 const float* __restrict__ ub, const float* __restrict__ vb,
                 short* __restrict__ qu, short* __restrict__ qv,
                 short* __restrict__ kb, short* __restrict__ vbuf,
                 short* __restrict__ pbuf) {
    const int z = blockIdx.z;
    const float* A; const float* W; int M;
    switch (z) {
        case 0:  A = xn; W = Wq; M = NROW;  break;
        case 1:  A = xn; W = Wk; M = NROW;  break;
        case 2:  A = xn; W = Wv; M = NROW;  break;
        default: A = pe; W = Wp; M = L_SEQ; break;
    }
    const int row0 = blockIdx.x * 128;
    if (row0 >= M) return;
    const int col0 = blockIdx.y * 128;
    float acc[8][8];
    gemm_core(A, W, row0, col0, acc);

    const int t = threadIdx.x;
    const int tx = t & 15, ty = t >> 4;
    #pragma unroll
    for (int i = 0; i < 8; ++i) {
        const int rr = row0 + ty*8 + i;
        #pragma unroll
        for (int j = 0; j < 8; ++j) {
            const int cc = col0 + tx*8 + j;
            const float a = acc[i][j];
            const size_t idx = (size_t)rr*DMODEL + cc;
            if (z == 0) {
                const float base = a + bq[cc];
                qu[idx] = f2bf(base + ub[cc]);
                qv[idx] = f2bf(base + vb[cc]);
            } else if (z == 1) {
                kb[idx] = f2bf(a + bk[cc]);
            } else if (z == 2) {
                vbuf[idx] = f2bf(a + bv[cc]);
            } else {
                pbuf[idx] = f2bf(a);
            }
        }
    }
}

// ---------------- final out GEMM (fp32) ----------------
__global__ __launch_bounds__(256)
void gemm_kernel(const float* __restrict__ A, const float* __restrict__ W,
                 const float* __restrict__ bias, float* __restrict__ C, int M) {
    const int row0 = blockIdx.x * 128;
    if (row0 >= M) return;
    const int col0 = blockIdx.y * 128;
    float acc[8][8];
    gemm_core(A, W, row0, col0, acc);
    const int t = threadIdx.x;
    const int tx = t & 15, ty = t >> 4;
    #pragma unroll
    for (int i = 0; i < 8; ++i) {
        const int rr = row0 + ty*8 + i;
        #pragma unroll
        for (int j4 = 0; j4 < 2; ++j4) {
            const int cc = col0 + tx*8 + j4*4;
            float4 o;
            o.x = acc[i][j4*4+0] + bias[cc+0];
            o.y = acc[i][j4*4+1] + bias[cc+1];
            o.z = acc[i][j4*4+2] + bias[cc+2];
            o.w = acc[i][j4*4+3] + bias[cc+3];
            *(float4*)(C + (size_t)rr*256 + cc) = o;
        }
    }
}

// ---------------- V transpose: v[b,l,h,d] -> vT[b,h,d,l] ----------------
__global__ __launch_bounds__(256)
void vtrans_kernel(const short* __restrict__ v, short* __restrict__ vT) {
    const int l0 = blockIdx.x * 64;
    const int h  = blockIdx.y;
    const int b  = blockIdx.z;
    const int t  = threadIdx.x;
    __shared__ short s[32][72];
    const int r = t & 63, c8 = (t >> 6) * 8;
    short8 val = *(const short8*)(v + ((size_t)(b*L_SEQ + l0 + r))*DMODEL + h*DHEAD + c8);
    #pragma unroll
    for (int j = 0; j < 8; ++j) s[c8+j][r] = val[j];
    __syncthreads();
    const int d = t >> 3, l8 = (t & 7) * 8;
    *(short8*)(vT + (((size_t)((b*NH + h)*DHEAD + d))*L_SEQ) + l0 + l8) = *(const short8*)&s[d][l8];
}

// ---------------- fused MFMA attention with Transformer-XL rel-shift ----------------
// Block = 256 threads (4 waves), one (b, h, 64-row q-tile).
// sTt stride 67 (odd dword stride -> conflict-free diagonal gather).
// pfrag register rotation: jj-window slides by 64/tile, rho invariant -> reuse 4 of 8 frags.
// Loads for next tile issued after barrier1, drained at barrier2 (hidden under softmax).
// Extra T row (qi=64) computed by wave 3 via MFMA on resident pfrag (A = qv rows q0+49..64).
__global__ __launch_bounds__(256, 3)
void attn_mfma_kernel(const short* __restrict__ qu, const short* __restrict__ qv,
                      const short* __restrict__ kb, const short* __restrict__ pb,
                      const short* __restrict__ vT, float* __restrict__ ctx) {
    const int q0 = blockIdx.x * 64;
    const int h  = blockIdx.y;
    const int b  = blockIdx.z;
    const int t  = threadIdx.x;
    const int w  = t >> 6;
    const int l  = t & 63;
    const int lc = l & 15;
    const int lg = l >> 4;

    __shared__ float sTt[128][67];   // [jj][qi 0..64] pos scores (transposed), odd stride
    __shared__ short sP[64][72];     // softmax probs, bf16

    // A-fragments: rows q0+16w+lc, k = lg*8..+8 (held across all k-tiles)
    const size_t qrow = ((size_t)(b*L_SEQ + q0 + 16*w + lc))*DMODEL + h*DHEAD + lg*8;
    const short8 aqu = *(const short8*)(qu + qrow);
    const short8 aqv = *(const short8*)(qv + qrow);
    // shifted A (rows q0+49..q0+64) for the extra T row, used by wave 3
    short8 aqv_sh = zero8();
    {
        const int r2 = q0 + 49 + lc;
        if (r2 < L_SEQ)
            aqv_sh = *(const short8*)(qv + ((size_t)(b*L_SEQ + r2))*DMODEL + h*DHEAD + lg*8);
    }

    float m_r[4], l_r[4], alpha[4];
    f32x4 acc0, acc1;
    #pragma unroll
    for (int r = 0; r < 4; ++r) { m_r[r] = -3.0e38f; l_r[r] = 0.f; acc0[r] = 0.f; acc1[r] = 0.f; }

    const short* kbase = kb + ((size_t)(b*L_SEQ))*DMODEL + h*DHEAD;
    const short* pbase = pb + h*DHEAD;
    const short* vbase = vT + ((size_t)((b*NH + h)*DHEAD))*L_SEQ;
    const f32x4 zf = {0.f, 0.f, 0.f, 0.f};
    const float KSC = 0.0625f * 1.44269504088896340736f;  // (1/16)*log2(e)

    const int jbase0 = -q0 - 65;   // jbase for k0 = 0

    // p-fragment loader: tile index cc relative to jbase0 + current k0 offset handled by caller
    auto loadP = [&](int jb, int cc) -> short8 {
        const int rho = jb + cc*16 + lc;
        if (rho == -1) return zero8();
        const int pr = rho + (rho < 0 ? (L_SEQ+1) : 0);
        return *(const short8*)(pbase + (size_t)pr*DMODEL + lg*8);
    };

    // persistent fragments
    short8 kfrag[4], pfrag[8], vfrag[4];
    #pragma unroll
    for (int ct = 0; ct < 4; ++ct)
        kfrag[ct] = *(const short8*)(kbase + (size_t)(ct*16 + lc)*DMODEL + lg*8);
    #pragma unroll
    for (int ct = 0; ct < 8; ++ct) pfrag[ct] = loadP(jbase0, ct);

    for (int k0 = 0; k0 < L_SEQ; k0 += 64) {
        const int jbase = k0 - q0 - 65;   // rho = jbase + jj

        // ---- content scores: 4 col tiles (kfrag resident) ----
        f32x4 c[4];
        #pragma unroll
        for (int ct = 0; ct < 4; ++ct)
            c[ct] = __builtin_amdgcn_mfma_f32_16x16x32_bf16(aqu, kfrag[ct], zf, 0, 0, 0);

        // ---- pos band: T[qi][jj] -> sTt (pfrag resident) ----
        #pragma unroll
        for (int ct = 0; ct < 8; ++ct) {
            f32x4 tt = __builtin_amdgcn_mfma_f32_16x16x32_bf16(aqv, pfrag[ct], zf, 0, 0, 0);
            *(f32x4*)&sTt[ct*16 + lc][16*w + lg*4] = tt;
        }
        // ---- extra row qi=64 via wave 3 (C row 15 = rows q0+64) ----
        if (w == 3) {
            #pragma unroll
            for (int ct = 0; ct < 8; ++ct) {
                f32x4 tt2 = __builtin_amdgcn_mfma_f32_16x16x32_bf16(aqv_sh, pfrag[ct], zf, 0, 0, 0);
                if (lg == 3) sTt[ct*16 + lc][64] = tt2[3];
            }
        }
        // ---- rotate p-window (slide by 64: next[0..3] = cur[4..7]) ----
        #pragma unroll
        for (int i = 0; i < 4; ++i) pfrag[i] = pfrag[i+4];

        __syncthreads();    // barrier 1: sTt visible

        // ---- issue next-tile / current-V loads (drained at barrier 2) ----
        if (k0 + 64 < L_SEQ) {
            #pragma unroll
            for (int ct = 0; ct < 4; ++ct)
                kfrag[ct] = *(const short8*)(kbase + (size_t)(k0 + 64 + ct*16 + lc)*DMODEL + lg*8);
            #pragma unroll
            for (int i = 0; i < 4; ++i) pfrag[4+i] = loadP(jbase, 8+i);
        }
        #pragma unroll
        for (int kc = 0; kc < 2; ++kc) {
            vfrag[kc*2+0] = *(const short8*)(vbase + (size_t)(lc)*L_SEQ      + k0 + kc*32 + lg*8);
            vfrag[kc*2+1] = *(const short8*)(vbase + (size_t)(16 + lc)*L_SEQ + k0 + kc*32 + lg*8);
        }

        // ---- combine + online softmax (state in regs; row = 16w + 4lg + r) ----
        #pragma unroll
        for (int r = 0; r < 4; ++r) {
            const int qi = 16*w + lg*4 + r;
            float sc[4];
            #pragma unroll
            for (int ct = 0; ct < 4; ++ct) {
                const int ki = ct*16 + lc;
                const int jj = ki - qi + 63;
                const int up = (jbase + jj) >= 0 ? 1 : 0;
                sc[ct] = (c[ct][r] + sTt[jj][qi + up]) * KSC;
            }
            float mx = fmaxf(fmaxf(sc[0], sc[1]), fmaxf(sc[2], sc[3]));
            #pragma unroll
            for (int o = 8; o; o >>= 1) mx = fmaxf(mx, __shfl_xor(mx, o));
            const float mn = fmaxf(m_r[r], mx);
            float ts = 0.f;
            #pragma unroll
            for (int ct = 0; ct < 4; ++ct) { sc[ct] = exp2f(sc[ct] - mn); ts += sc[ct]; }
            #pragma unroll
            for (int o = 8; o; o >>= 1) ts += __shfl_xor(ts, o);
            alpha[r] = exp2f(m_r[r] - mn);
            m_r[r] = mn;
            l_r[r] = l_r[r]*alpha[r] + ts;
            #pragma unroll
            for (int ct = 0; ct < 4; ++ct) sP[qi][ct*16 + lc] = f2bf(sc[ct]);
        }
        #pragma unroll
        for (int r = 0; r < 4; ++r) { acc0[r] *= alpha[r]; acc1[r] *= alpha[r]; }

        __syncthreads();    // barrier 2: sP visible, prefetch drained

        // ---- PV: A = own P rows (LDS), B = vfrag (regs) ----
        #pragma unroll
        for (int kc = 0; kc < 2; ++kc) {
            const short8 ap = *(const short8*)&sP[16*w + lc][kc*32 + lg*8];
            acc0 = __builtin_amdgcn_mfma_f32_16x16x32_bf16(ap, vfrag[kc*2+0], acc0, 0, 0, 0);
            acc1 = __builtin_amdgcn_mfma_f32_16x16x32_bf16(ap, vfrag[kc*2+1], acc1, 0, 0, 0);
        }
        __syncthreads();    // barrier 3: sP/sTt reads done before next tile writes
    }

    #pragma unroll
    for (int r = 0; r < 4; ++r) {
        const float inv = 1.f / l_r[r];
        const size_t orow = ((size_t)(b*L_SEQ + q0 + 16*w + lg*4 + r))*DMODEL + h*DHEAD;
        ctx[orow + lc]      = acc0[r] * inv;
        ctx[orow + 16 + lc] = acc1[r] * inv;
    }
}

extern "C" void kernel_launch(void* const* d_in, const int* in_sizes, int n_in,
                              void* d_out, int out_size, void* d_ws, size_t ws_size,
                              hipStream_t stream) {
    (void)in_sizes; (void)n_in; (void)out_size; (void)ws_size;
    const float* x     = (const float*)d_in[0];
    const float* gamma = (const float*)d_in[1];
    const float* beta  = (const float*)d_in[2];
    const float* Wq    = (const float*)d_in[3];
    const float* bq    = (const float*)d_in[4];
    const float* Wk    = (const float*)d_in[5];
    const float* bk    = (const float*)d_in[6];
    const float* Wv    = (const float*)d_in[7];
    const float* bv    = (const float*)d_in[8];
    const float* Wp    = (const float*)d_in[9];
    const float* ub    = (const float*)d_in[10];
    const float* vb    = (const float*)d_in[11];
    const float* Wo    = (const float*)d_in[12];
    const float* bo    = (const float*)d_in[13];
    float* out = (float*)d_out;

    char* wsb = (char*)d_ws;
    float* ctx = (float*)wsb;                                   // 8192*256 f32 (aliases xn)
    float* xn  = ctx;
    float* pe  = (float*)(wsb + (size_t)8388608);               // 2048*256 f32
    short* qu  = (short*)(wsb + (size_t)8388608 + 2097152);     // bf16 buffers
    short* qv  = qu + (size_t)NROW*DMODEL;
    short* kbf = qv + (size_t)NROW*DMODEL;
    short* vbf = kbf + (size_t)NROW*DMODEL;
    short* vT  = vbf + (size_t)NROW*DMODEL;
    short* pbf = vT  + (size_t)NROW*DMODEL;                     // 2048*256 bf16

    pe_kernel<<<1024, 256, 0, stream>>>(pe);
    ln_kernel<<<2048, 256, 0, stream>>>(x, gamma, beta, xn);
    proj_kernel<<<dim3(64,2,4), 256, 0, stream>>>(xn, pe, Wq, bq, Wk, bk, Wv, bv, Wp,
                                                  ub, vb, qu, qv, kbf, vbf, pbf);
    vtrans_kernel<<<dim3(32,8,4), 256, 0, stream>>>(vbf, vT);
    attn_mfma_kernel<<<dim3(32,8,4), 256, 0, stream>>>(qu, qv, kbf, pbf, vT, ctx);
    gemm_kernel<<<dim3(64,2,1), 256, 0, stream>>>(ctx, Wo, bo, out, NROW);
}

// Round 4
// 360.521 us; speedup vs baseline: 11.2692x; 1.0546x over previous
//
#include <hip/hip_runtime.h>
#include <hip/hip_bf16.h>
#include <math.h>

#define L_SEQ 2048
#define NB 4
#define DMODEL 256
#define NH 8
#define DHEAD 32
#define NROW (NB*L_SEQ)

typedef __attribute__((ext_vector_type(8))) short short8;
typedef __attribute__((ext_vector_type(4))) float f32x4;

__device__ __forceinline__ short f2bf(float f) {
    union { float f; unsigned u; } x; x.f = f;
    unsigned r = x.u + 0x7fff + ((x.u >> 16) & 1);
    return (short)(r >> 16);
}
__device__ __forceinline__ short8 zero8() {
    short8 z;
    #pragma unroll
    for (int i = 0; i < 8; ++i) z[i] = 0;
    return z;
}

// ---------------- sinusoidal positional encoding ----------------
__global__ void pe_kernel(float* __restrict__ pe) {
    int idx = blockIdx.x*256 + threadIdx.x;      // 2048*128 total
    int l = idx >> 7, m = idx & 127;
    double ang = (double)l * exp((double)m * (-9.210340371976184/128.0));
    pe[l*DMODEL + 2*m]   = (float)sin(ang);
    pe[l*DMODEL + 2*m+1] = (float)cos(ang);
}

// ---------------- layernorm (one wave per row) ----------------
__global__ void ln_kernel(const float* __restrict__ x, const float* __restrict__ gamma,
                          const float* __restrict__ beta, float* __restrict__ xn) {
    int lane = threadIdx.x & 63;
    int row  = blockIdx.x*4 + (threadIdx.x >> 6);
    const float4 a = *(const float4*)(x + (size_t)row*DMODEL + lane*4);
    float s  = a.x+a.y+a.z+a.w;
    float s2 = a.x*a.x+a.y*a.y+a.z*a.z+a.w*a.w;
    #pragma unroll
    for (int o = 32; o; o >>= 1) { s += __shfl_xor(s,o); s2 += __shfl_xor(s2,o); }
    float mu  = s * (1.f/DMODEL);
    float var = s2 * (1.f/DMODEL) - mu*mu;
    float rst = rsqrtf(var + 1e-3f);
    const float4 g  = *(const float4*)(gamma + lane*4);
    const float4 bt = *(const float4*)(beta  + lane*4);
    float4 o;
    o.x = (a.x-mu)*rst*g.x + bt.x;
    o.y = (a.y-mu)*rst*g.y + bt.y;
    o.z = (a.z-mu)*rst*g.z + bt.z;
    o.w = (a.w-mu)*rst*g.w + bt.w;
    *(float4*)(xn + (size_t)row*DMODEL + lane*4) = o;
}

// ---------------- fp32 GEMM core (128x128 tile, 8x8 micro) ----------------
__device__ __forceinline__ void gemm_core(const float* __restrict__ A,
                                          const float* __restrict__ W,
                                          int row0, int col0, float acc[8][8]) {
    __shared__ float As[8][136];
    __shared__ float Ws[8][136];
    const int t  = threadIdx.x;
    const int tx = t & 15, ty = t >> 4;
    #pragma unroll
    for (int i = 0; i < 8; ++i)
        #pragma unroll
        for (int j = 0; j < 8; ++j) acc[i][j] = 0.f;

    const int ar = t >> 1, ac4 = t & 1;
    const int wr = t >> 5, wc4 = t & 31;

    for (int k0 = 0; k0 < 256; k0 += 8) {
        float4 av = *(const float4*)(A + (size_t)(row0+ar)*256 + k0 + ac4*4);
        As[ac4*4+0][ar] = av.x;
        As[ac4*4+1][ar] = av.y;
        As[ac4*4+2][ar] = av.z;
        As[ac4*4+3][ar] = av.w;
        *(float4*)&Ws[wr][wc4*4] = *(const float4*)(W + (size_t)(k0+wr)*256 + col0 + wc4*4);
        __syncthreads();
        #pragma unroll
        for (int kk = 0; kk < 8; ++kk) {
            float a8[8], b8[8];
            *(float4*)&a8[0] = *(const float4*)&As[kk][ty*8];
            *(float4*)&a8[4] = *(const float4*)&As[kk][ty*8+4];
            *(float4*)&b8[0] = *(const float4*)&Ws[kk][tx*8];
            *(float4*)&b8[4] = *(const float4*)&Ws[kk][tx*8+4];
            #pragma unroll
            for (int i = 0; i < 8; ++i)
                #pragma unroll
                for (int j = 0; j < 8; ++j)
                    acc[i][j] += a8[i]*b8[j];
        }
        __syncthreads();
    }
}

// ---------------- projections -> bf16 (qu = q+u, qv = q+v_bias, k, v, p) ----------------
__global__ __launch_bounds__(256)
void proj_kernel(const float* __restrict__ xn, const float* __restrict__ pe,
                 const float* __restrict__ Wq, const float* __restrict__ bq,
                 const float* __restrict__ Wk, const float* __restrict__ bk,
                 const float* __restrict__ Wv, const float* __restrict__ bv,
                 const float* __restrict__ Wp,
                 const float* __restrict__ ub, const float* __restrict__ vb,
                 short* __restrict__ qu, short* __restrict__ qv,
                 short* __restrict__ kb, short* __restrict__ vbuf,
                 short* __restrict__ pbuf) {
    const int z = blockIdx.z;
    const float* A; const float* W; int M;
    switch (z) {
        case 0:  A = xn; W = Wq; M = NROW;  break;
        case 1:  A = xn; W = Wk; M = NROW;  break;
        case 2:  A = xn; W = Wv; M = NROW;  break;
        default: A = pe; W = Wp; M = L_SEQ; break;
    }
    const int row0 = blockIdx.x * 128;
    if (row0 >= M) return;
    const int col0 = blockIdx.y * 128;
    float acc[8][8];
    gemm_core(A, W, row0, col0, acc);

    const int t = threadIdx.x;
    const int tx = t & 15, ty = t >> 4;
    #pragma unroll
    for (int i = 0; i < 8; ++i) {
        const int rr = row0 + ty*8 + i;
        #pragma unroll
        for (int j = 0; j < 8; ++j) {
            const int cc = col0 + tx*8 + j;
            const float a = acc[i][j];
            const size_t idx = (size_t)rr*DMODEL + cc;
            if (z == 0) {
                const float base = a + bq[cc];
                qu[idx] = f2bf(base + ub[cc]);
                qv[idx] = f2bf(base + vb[cc]);
            } else if (z == 1) {
                kb[idx] = f2bf(a + bk[cc]);
            } else if (z == 2) {
                vbuf[idx] = f2bf(a + bv[cc]);
            } else {
                pbuf[idx] = f2bf(a);
            }
        }
    }
}

// ---------------- final out GEMM (fp32) ----------------
__global__ __launch_bounds__(256)
void gemm_kernel(const float* __restrict__ A, const float* __restrict__ W,
                 const float* __restrict__ bias, float* __restrict__ C, int M) {
    const int row0 = blockIdx.x * 128;
    if (row0 >= M) return;
    const int col0 = blockIdx.y * 128;
    float acc[8][8];
    gemm_core(A, W, row0, col0, acc);
    const int t = threadIdx.x;
    const int tx = t & 15, ty = t >> 4;
    #pragma unroll
    for (int i = 0; i < 8; ++i) {
        const int rr = row0 + ty*8 + i;
        #pragma unroll
        for (int j4 = 0; j4 < 2; ++j4) {
            const int cc = col0 + tx*8 + j4*4;
            float4 o;
            o.x = acc[i][j4*4+0] + bias[cc+0];
            o.y = acc[i][j4*4+1] + bias[cc+1];
            o.z = acc[i][j4*4+2] + bias[cc+2];
            o.w = acc[i][j4*4+3] + bias[cc+3];
            *(float4*)(C + (size_t)rr*256 + cc) = o;
        }
    }
}

// ---------------- V transpose: v[b,l,h,d] -> vT[b,h,d,l] ----------------
__global__ __launch_bounds__(256)
void vtrans_kernel(const short* __restrict__ v, short* __restrict__ vT) {
    const int l0 = blockIdx.x * 64;
    const int h  = blockIdx.y;
    const int b  = blockIdx.z;
    const int t  = threadIdx.x;
    __shared__ short s[32][72];
    const int r = t & 63, c8 = (t >> 6) * 8;
    short8 val = *(const short8*)(v + ((size_t)(b*L_SEQ + l0 + r))*DMODEL + h*DHEAD + c8);
    #pragma unroll
    for (int j = 0; j < 8; ++j) s[c8+j][r] = val[j];
    __syncthreads();
    const int d = t >> 3, l8 = (t & 7) * 8;
    *(short8*)(vT + (((size_t)((b*NH + h)*DHEAD + d))*L_SEQ) + l0 + l8) = *(const short8*)&s[d][l8];
}

// ---------------- fused MFMA attention, swapped-operand layout ----------------
// Block = 256 threads (4 waves), one (b, h, 64-row q-tile).
// S^T = mfma(K, Qu): lane (lc,lg) reg r holds S[k0+16ct+4lg+r][q0+16w+lc] -> lane owns
// ONE q-row => softmax reduction = in-reg + 2 shfls. T^T = mfma(ptilde, Qv) written to
// sT[qi][jj] (b128, contiguous jj); rel-shift gather = 16 scalar reads sT[qi+up][jj],
// jj = ki-qi+63, ~2-way banks at stride 132. P packed via v_cvt_pk_bf16_f32 into
// XOR-block-swizzled sPk[64][32] u32 (4 b64 writes, 2 b128 reads, intra-wave).
// PV swapped: ctx^T = mfma(V^T, P). Epilogue transposes through sPk for coalesced stores.
__global__ __launch_bounds__(256, 3)
void attn_mfma_kernel(const short* __restrict__ qu, const short* __restrict__ qv,
                      const short* __restrict__ kb, const short* __restrict__ pb,
                      const short* __restrict__ vT, float* __restrict__ ctx) {
    const int q0 = blockIdx.x * 64;
    const int h  = blockIdx.y;
    const int b  = blockIdx.z;
    const int t  = threadIdx.x;
    const int w  = t >> 6;
    const int l  = t & 63;
    const int lc = l & 15;
    const int lg = l >> 4;

    __shared__ float    sT[65][132];   // [qi][jj] pos scores; stride 132 (b128-aligned, 2-way gather)
    __shared__ unsigned sPk[64][32];   // P as bf16 pairs, XOR-block-swizzled; reused as ctx tile

    // B-fragments: Q rows 16w+lc (wave-own), k = lg*8..+8, resident all tiles
    const size_t qrow = ((size_t)(b*L_SEQ + q0 + 16*w + lc))*DMODEL + h*DHEAD + lg*8;
    const short8 aqu = *(const short8*)(qu + qrow);
    const short8 aqv = *(const short8*)(qv + qrow);
    // shifted Qv (rows q0+49..q0+64) for the extra T row: col lc=15 <-> row q0+64
    short8 aqv_sh = zero8();
    {
        const int r2 = q0 + 49 + lc;
        if (r2 < L_SEQ)
            aqv_sh = *(const short8*)(qv + ((size_t)(b*L_SEQ + r2))*DMODEL + h*DHEAD + lg*8);
    }

    float m_r = -3.0e38f, l_r = 0.f;
    f32x4 acc0 = {0.f,0.f,0.f,0.f}, acc1 = {0.f,0.f,0.f,0.f};

    const short* kbase = kb + ((size_t)(b*L_SEQ))*DMODEL + h*DHEAD;
    const short* pbase = pb + h*DHEAD;
    const short* vbase = vT + ((size_t)((b*NH + h)*DHEAD))*L_SEQ;
    const f32x4 zf = {0.f, 0.f, 0.f, 0.f};
    const float KSC = 0.0625f * 1.44269504088896340736f;  // (1/16)*log2(e)

    const int jbase0 = -q0 - 65;
    auto loadP = [&](int jb, int cc) -> short8 {
        const int rho = jb + cc*16 + lc;
        if (rho == -1) return zero8();
        const int pr = rho + (rho < 0 ? (L_SEQ+1) : 0);
        return *(const short8*)(pbase + (size_t)pr*DMODEL + lg*8);
    };

    // persistent A-fragments (K rows / ptilde rows, row index = lc)
    short8 kfrag[4], pfrag[8];
    #pragma unroll
    for (int ct = 0; ct < 4; ++ct)
        kfrag[ct] = *(const short8*)(kbase + (size_t)(ct*16 + lc)*DMODEL + lg*8);
    #pragma unroll
    for (int ct = 0; ct < 8; ++ct) pfrag[ct] = loadP(jbase0, ct);

    const int jjc = 4*lg + 63 - 16*w - lc;     // jj = jjc + 16*ct + r
    const int qi  = 16*w + lc;
    const int swkey = lc & 7;

    for (int k0 = 0; k0 < L_SEQ; k0 += 64) {
        const int diff = k0 - q0;

        // ---- content: S^T tiles (A = K, B = Qu) ----
        f32x4 cts[4];
        #pragma unroll
        for (int ct = 0; ct < 4; ++ct)
            cts[ct] = __builtin_amdgcn_mfma_f32_16x16x32_bf16(kfrag[ct], aqu, zf, 0, 0, 0);

        // ---- pos band: T^T[jj][qi] -> sT[qi][jj] (contiguous b128 writes) ----
        #pragma unroll
        for (int ct = 0; ct < 8; ++ct) {
            f32x4 tt = __builtin_amdgcn_mfma_f32_16x16x32_bf16(pfrag[ct], aqv, zf, 0, 0, 0);
            *(f32x4*)&sT[qi][16*ct + 4*lg] = tt;
        }
        // extra row qi=64 (wave 3; col lc=15 of shifted-Q MFMA)
        if (w == 3) {
            #pragma unroll
            for (int ct = 0; ct < 8; ++ct) {
                f32x4 tt2 = __builtin_amdgcn_mfma_f32_16x16x32_bf16(pfrag[ct], aqv_sh, zf, 0, 0, 0);
                if (lc == 15) *(f32x4*)&sT[64][16*ct + 4*lg] = tt2;
            }
        }
        // rotate p-window (slide 64: next[0..3] = cur[4..7])
        #pragma unroll
        for (int i = 0; i < 4; ++i) pfrag[i] = pfrag[i+4];

        __syncthreads();   // barrier 1: sT complete

        // ---- issue next-tile K/p and current V loads (consumed after softmax) ----
        if (k0 + 64 < L_SEQ) {
            #pragma unroll
            for (int ct = 0; ct < 4; ++ct)
                kfrag[ct] = *(const short8*)(kbase + (size_t)(k0 + 64 + ct*16 + lc)*DMODEL + lg*8);
            const int jbase = diff - q0 + k0 - k0 - 65 + q0;  // = k0 - q0 - 65
            #pragma unroll
            for (int i = 0; i < 4; ++i) pfrag[4+i] = loadP(k0 - q0 - 65, 8+i);
            (void)jbase;
        }
        short8 vfrag[2][2];
        #pragma unroll
        for (int dt = 0; dt < 2; ++dt)
            #pragma unroll
            for (int kc = 0; kc < 2; ++kc)
                vfrag[dt][kc] = *(const short8*)(vbase + (size_t)(16*dt + lc)*L_SEQ + k0 + kc*32 + lg*8);

        // ---- rel-shift gather + combine ----
        float sc[4][4];
        const bool uni = (diff <= -64) || (diff >= 128);
        if (uni) {
            const float* rowp = &sT[qi + (diff >= 128 ? 1 : 0)][0];
            #pragma unroll
            for (int ct = 0; ct < 4; ++ct)
                #pragma unroll
                for (int r = 0; r < 4; ++r)
                    sc[ct][r] = (cts[ct][r] + rowp[jjc + 16*ct + r]) * KSC;
        } else {
            const int thr = 65 - diff;
            #pragma unroll
            for (int ct = 0; ct < 4; ++ct)
                #pragma unroll
                for (int r = 0; r < 4; ++r) {
                    const int jj = jjc + 16*ct + r;
                    const int up = (jj >= thr) ? 1 : 0;
                    sc[ct][r] = (cts[ct][r] + sT[qi + up][jj]) * KSC;
                }
        }
        __syncthreads();   // barrier 2: sT reads done (next tile may overwrite)

        // ---- softmax: lane owns row qi; in-reg reduce + 2 shfls ----
        float mx = sc[0][0];
        #pragma unroll
        for (int ct = 0; ct < 4; ++ct)
            #pragma unroll
            for (int r = 0; r < 4; ++r) mx = fmaxf(mx, sc[ct][r]);
        mx = fmaxf(mx, __shfl_xor(mx, 16));
        mx = fmaxf(mx, __shfl_xor(mx, 32));
        const float mn = fmaxf(m_r, mx);
        float ts = 0.f;
        #pragma unroll
        for (int ct = 0; ct < 4; ++ct)
            #pragma unroll
            for (int r = 0; r < 4; ++r) { sc[ct][r] = exp2f(sc[ct][r] - mn); ts += sc[ct][r]; }
        ts += __shfl_xor(ts, 16);
        ts += __shfl_xor(ts, 32);
        const float alpha = exp2f(m_r - mn);
        m_r = mn;
        l_r = l_r*alpha + ts;

        // ---- pack P -> sPk (bf16 pairs, XOR-block swizzle) ----
        #pragma unroll
        for (int ct = 0; ct < 4; ++ct) {
            unsigned lo, hi;
            asm("v_cvt_pk_bf16_f32 %0, %1, %2" : "=v"(lo) : "v"(sc[ct][0]), "v"(sc[ct][1]));
            asm("v_cvt_pk_bf16_f32 %0, %1, %2" : "=v"(hi) : "v"(sc[ct][2]), "v"(sc[ct][3]));
            const int kbi = 2*ct + (lg >> 1);
            const int idx = ((kbi ^ swkey) << 2) + 2*(lg & 1);
            *(uint2*)&sPk[qi][idx] = make_uint2(lo, hi);
        }
        #pragma unroll
        for (int r = 0; r < 4; ++r) { acc0[r] *= alpha; acc1[r] *= alpha; }

        // ---- PV: ctx^T += V^T . P  (A = vfrag, B = P from sPk) ----
        #pragma unroll
        for (int kc = 0; kc < 2; ++kc) {
            const int idx = ((4*kc + lg) ^ swkey) << 2;
            const short8 bp = *(const short8*)&sPk[qi][idx];
            acc0 = __builtin_amdgcn_mfma_f32_16x16x32_bf16(vfrag[0][kc], bp, acc0, 0, 0, 0);
            acc1 = __builtin_amdgcn_mfma_f32_16x16x32_bf16(vfrag[1][kc], bp, acc1, 0, 0, 0);
        }
    }

    // ---- epilogue: transpose ctx^T -> ctx via sPk space (per-wave rows) ----
    __syncthreads();
    float* sCt = (float*)&sPk[0][0];   // [64][32] f32 view
    const float inv = 1.f / l_r;
    {
        f32x4 o0, o1;
        #pragma unroll
        for (int r = 0; r < 4; ++r) { o0[r] = acc0[r]*inv; o1[r] = acc1[r]*inv; }
        *(f32x4*)&sCt[qi*32 + 4*lg]      = o0;
        *(f32x4*)&sCt[qi*32 + 16 + 4*lg] = o1;
    }
    __syncthreads();
    const int rr = 16*w + (l >> 2);
    const int c0 = (l & 3) * 8;
    float4 o0 = *(float4*)&sCt[rr*32 + c0];
    float4 o1 = *(float4*)&sCt[rr*32 + c0 + 4];
    float* orow = ctx + ((size_t)(b*L_SEQ + q0 + rr))*DMODEL + h*DHEAD + c0;
    *(float4*)orow     = o0;
    *(float4*)(orow+4) = o1;
}

extern "C" void kernel_launch(void* const* d_in, const int* in_sizes, int n_in,
                              void* d_out, int out_size, void* d_ws, size_t ws_size,
                              hipStream_t stream) {
    (void)in_sizes; (void)n_in; (void)out_size; (void)ws_size;
    const float* x     = (const float*)d_in[0];
    const float* gamma = (const float*)d_in[1];
    const float* beta  = (const float*)d_in[2];
    const float* Wq    = (const float*)d_in[3];
    const float* bq    = (const float*)d_in[4];
    const float* Wk    = (const float*)d_in[5];
    const float* bk    = (const float*)d_in[6];
    const float* Wv    = (const float*)d_in[7];
    const float* bv    = (const float*)d_in[8];
    const float* Wp    = (const float*)d_in[9];
    const float* ub    = (const float*)d_in[10];
    const float* vb    = (const float*)d_in[11];
    const float* Wo    = (const float*)d_in[12];
    const float* bo    = (const float*)d_in[13];
    float* out = (float*)d_out;

    char* wsb = (char*)d_ws;
    float* ctx = (float*)wsb;                                   // 8192*256 f32 (aliases xn)
    float* xn  = ctx;
    float* pe  = (float*)(wsb + (size_t)8388608);               // 2048*256 f32
    short* qu  = (short*)(wsb + (size_t)8388608 + 2097152);     // bf16 buffers
    short* qv  = qu + (size_t)NROW*DMODEL;
    short* kbf = qv + (size_t)NROW*DMODEL;
    short* vbf = kbf + (size_t)NROW*DMODEL;
    short* vT  = vbf + (size_t)NROW*DMODEL;
    short* pbf = vT  + (size_t)NROW*DMODEL;                     // 2048*256 bf16

    pe_kernel<<<1024, 256, 0, stream>>>(pe);
    ln_kernel<<<2048, 256, 0, stream>>>(x, gamma, beta, xn);
    proj_kernel<<<dim3(64,2,4), 256, 0, stream>>>(xn, pe, Wq, bq, Wk, bk, Wv, bv, Wp,
                                                  ub, vb, qu, qv, kbf, vbf, pbf);
    vtrans_kernel<<<dim3(32,8,4), 256, 0, stream>>>(vbf, vT);
    attn_mfma_kernel<<<dim3(32,8,4), 256, 0, stream>>>(qu, qv, kbf, pbf, vT, ctx);
    gemm_kernel<<<dim3(64,2,1), 256, 0, stream>>>(ctx, Wo, bo, out, NROW);
}